// Round 5
// baseline (258.454 us; speedup 1.0000x reference)
//
#include <hip/hip_runtime.h>

#define N_NODES 10000
#define E_EDGES 160000
#define IN_DIM  512
#define HID_DIM 512
#define OUT_DIM 256

typedef __attribute__((ext_vector_type(8))) short short8;
typedef __attribute__((ext_vector_type(4))) float f32x4;
typedef __attribute__((ext_vector_type(16))) float f32x16;

__device__ __forceinline__ unsigned short f2bh(float f) {
  union { float f; unsigned u; } v; v.f = f;
  return (unsigned short)((v.u + 0x7FFFu + ((v.u >> 16) & 1u)) >> 16);
}
__device__ __forceinline__ float bh2f(unsigned short h) {
  union { unsigned u; float f; } v; v.u = ((unsigned)h) << 16;
  return v.f;
}

// ===========================================================================
// CSR build: count -> exclusive scan (+dis) -> place
// ===========================================================================
__global__ void count_kernel(const int* __restrict__ dst, int* __restrict__ cnt) {
  int e = blockIdx.x * 256 + threadIdx.x;
  if (e < E_EDGES) atomicAdd(&cnt[dst[e]], 1);
}

__global__ __launch_bounds__(1024) void scan_kernel(
    int* __restrict__ cnt, int* __restrict__ row, float* __restrict__ dis) {
  __shared__ int sums[1024];
  const int CH = 10;
  int t = threadIdx.x;
  int c[CH], excl[CH];
  int s = 0;
#pragma unroll
  for (int j = 0; j < CH; ++j) {
    int idx = t * CH + j;
    c[j] = (idx < N_NODES) ? cnt[idx] : 0;
    excl[j] = s;
    s += c[j];
  }
  sums[t] = s;
  __syncthreads();
  for (int off = 1; off < 1024; off <<= 1) {
    int v = (t >= off) ? sums[t - off] : 0;
    __syncthreads();
    if (t >= off) sums[t] += v;
    __syncthreads();
  }
  int base = (t == 0) ? 0 : sums[t - 1];
#pragma unroll
  for (int j = 0; j < CH; ++j) {
    int idx = t * CH + j;
    if (idx < N_NODES) {
      int start = base + excl[j];
      row[idx] = start;
      cnt[idx] = start;  // cursor
      dis[idx] = rsqrtf((float)c[j] + 1.0f);
    }
  }
  if (t == 1023) row[N_NODES] = sums[1023];
}

__global__ void place_kernel(const int* __restrict__ src, const int* __restrict__ dst,
                             int* __restrict__ cursor, int* __restrict__ col) {
  int e = blockIdx.x * 256 + threadIdx.x;
  if (e < E_EDGES) {
    int pos = atomicAdd(&cursor[dst[e]], 1);
    col[pos] = src[e];
  }
}

// ===========================================================================
// GIN aggregation (gather): agg[i] = sum_{s in N(i)} x[s]
// ===========================================================================
__global__ __launch_bounds__(128) void gin_gather_kernel(
    const float* __restrict__ x, const int* __restrict__ row,
    const int* __restrict__ col, float* __restrict__ agg) {
  int i = blockIdx.x, t = threadIdx.x;
  int beg = row[i], end = row[i + 1];
  float4 acc{0.f, 0.f, 0.f, 0.f};
  for (int e = beg; e < end; ++e) {
    int s = col[e];
    float4 v = *reinterpret_cast<const float4*>(x + (size_t)s * IN_DIM + t * 4);
    acc.x += v.x; acc.y += v.y; acc.z += v.z; acc.w += v.w;
  }
  *reinterpret_cast<float4*>(agg + (size_t)i * IN_DIM + t * 4) = acc;
}

// ===========================================================================
// GCN aggregation (gather) fused with self-loop + bias
// ===========================================================================
__global__ __launch_bounds__(64) void gcn_gather_kernel(
    const float* __restrict__ h, const int* __restrict__ row,
    const int* __restrict__ col, const float* __restrict__ dis,
    const float* __restrict__ gcn_b, float* __restrict__ outg) {
  int i = blockIdx.x, t = threadIdx.x;
  int beg = row[i], end = row[i + 1];
  float di = dis[i];
  float4 acc{0.f, 0.f, 0.f, 0.f};
  for (int e = beg; e < end; ++e) {
    int s = col[e];
    float w = dis[s];
    float4 v = *reinterpret_cast<const float4*>(h + (size_t)s * OUT_DIM + t * 4);
    acc.x += w * v.x; acc.y += w * v.y; acc.z += w * v.z; acc.w += w * v.w;
  }
  float4 hv = *reinterpret_cast<const float4*>(h + (size_t)i * OUT_DIM + t * 4);
  float4 bv = *reinterpret_cast<const float4*>(gcn_b + t * 4);
  float self = di * di;
  float4 o{di * acc.x + self * hv.x + bv.x, di * acc.y + self * hv.y + bv.y,
           di * acc.z + self * hv.z + bv.z, di * acc.w + self * hv.w + bv.w};
  *reinterpret_cast<float4*>(outg + (size_t)i * OUT_DIM + t * 4) = o;
}

// ===========================================================================
// Weight transpose + bf16 hi/lo split: W [K][N] fp32 -> Wt_hi/lo [N][K] bf16
// ===========================================================================
__global__ void convT_kernel(const float* __restrict__ W, unsigned short* __restrict__ hi,
                             unsigned short* __restrict__ lo, int K, int N) {
  int k = blockIdx.x * 256 + threadIdx.x;
  int n = blockIdx.y;
  float a = W[(size_t)k * N + n];
  unsigned short h = f2bh(a);
  hi[(size_t)n * K + k] = h;
  lo[(size_t)n * K + k] = f2bh(a - bh2f(h));
}

// ===========================================================================
// Split-bf16 MFMA GEMM v2: 32x32x16, BM=128, BN=NW*64, 4 waves (2x2 grid),
// wave tile = 64 x NW*32 (2 x NW tiles of 32x32).
// LDS in fragment-chunk order: chunk c=[mt|s|kh|lane32], byte off = c*16.
// Staging: thread t writes chunk t (+256) -> strictly lane-linear ds_write,
// zero bank conflicts; global source address is permuted instead.
// A rows: k<kSplit from A0 (lda=kSplit) else A1 (lda=K-kSplit).
// ===========================================================================
template <bool BIAS, int NW>
__global__ __launch_bounds__(256) void mfma_gemm_kernel(
    const float* __restrict__ A0, const float* __restrict__ A1, int kSplit,
    const unsigned short* __restrict__ Wt_hi, const unsigned short* __restrict__ Wt_lo,
    const float* __restrict__ bias, float* __restrict__ C,
    int M, int K, int N) {
  __shared__ short8 Ahi[512];
  __shared__ short8 Alo[512];
  __shared__ short8 Bhi[NW * 256];
  __shared__ short8 Blo[NW * 256];

  int t = threadIdx.x;
  int w = t >> 6, l = t & 63;
  int wr = w >> 1, wc = w & 1;
  int brow = blockIdx.y * 128, bcol = blockIdx.x * (NW * 64);

  f32x16 acc[2][NW];
#pragma unroll
  for (int m = 0; m < 2; ++m)
#pragma unroll
    for (int n = 0; n < NW; ++n)
#pragma unroll
      for (int r = 0; r < 16; ++r) acc[m][n][r] = 0.f;

  for (int k0 = 0; k0 < K; k0 += 32) {
    const float* Ap; int kk, lda;
    if (k0 < kSplit) { Ap = A0; kk = k0; lda = kSplit; }
    else             { Ap = A1; kk = k0 - kSplit; lda = K - kSplit; }

    // ---- stage A: chunks t and t+256 (linear LDS writes)
#pragma unroll
    for (int cc = 0; cc < 2; ++cc) {
      int c = t + cc * 256;
      int mt = c >> 7, si = (c >> 6) & 1, kh = (c >> 5) & 1, lr = c & 31;
      int arow = brow + mt * 32 + lr;
      int ak = kk + si * 16 + kh * 8;
      short8 ph, pl;
      if (arow < M) {
        const float* p = Ap + (size_t)arow * lda + ak;
        float4 u0 = *reinterpret_cast<const float4*>(p);
        float4 u1 = *reinterpret_cast<const float4*>(p + 4);
        float va[8] = {u0.x, u0.y, u0.z, u0.w, u1.x, u1.y, u1.z, u1.w};
#pragma unroll
        for (int j = 0; j < 8; ++j) {
          unsigned short hh = f2bh(va[j]);
          ph[j] = (short)hh;
          pl[j] = (short)f2bh(va[j] - bh2f(hh));
        }
      } else {
#pragma unroll
        for (int j = 0; j < 8; ++j) { ph[j] = 0; pl[j] = 0; }
      }
      Ahi[c] = ph;
      Alo[c] = pl;
    }
    // ---- stage B: NW chunks (straight 16B copies, linear LDS writes)
#pragma unroll
    for (int cc = 0; cc < NW; ++cc) {
      int c = t + cc * 256;
      int nt = c >> 7, si = (c >> 6) & 1, kh = (c >> 5) & 1, lc = c & 31;
      int bcl = bcol + nt * 32 + lc;
      size_t off = (size_t)bcl * K + k0 + si * 16 + kh * 8;
      Bhi[c] = *reinterpret_cast<const short8*>(Wt_hi + off);
      Blo[c] = *reinterpret_cast<const short8*>(Wt_lo + off);
    }
    __syncthreads();

#pragma unroll
    for (int si = 0; si < 2; ++si) {
      short8 ah[2], al[2], bh[NW], bl[NW];
#pragma unroll
      for (int m = 0; m < 2; ++m) {
        int c = (wr * 2 + m) * 128 + si * 64 + l;
        ah[m] = Ahi[c];
        al[m] = Alo[c];
      }
#pragma unroll
      for (int n = 0; n < NW; ++n) {
        int c = (wc * NW + n) * 128 + si * 64 + l;
        bh[n] = Bhi[c];
        bl[n] = Blo[c];
      }
#pragma unroll
      for (int m = 0; m < 2; ++m)
#pragma unroll
        for (int n = 0; n < NW; ++n) {
          acc[m][n] = __builtin_amdgcn_mfma_f32_32x32x16_bf16(ah[m], bh[n], acc[m][n], 0, 0, 0);
          acc[m][n] = __builtin_amdgcn_mfma_f32_32x32x16_bf16(al[m], bh[n], acc[m][n], 0, 0, 0);
          acc[m][n] = __builtin_amdgcn_mfma_f32_32x32x16_bf16(ah[m], bl[n], acc[m][n], 0, 0, 0);
        }
    }
    __syncthreads();
  }

  // epilogue: 32x32 C/D layout col=lane&31, row=(r&3)+8*(r>>2)+4*(lane>>5)
#pragma unroll
  for (int m = 0; m < 2; ++m) {
    int r0 = brow + (wr * 2 + m) * 32 + 4 * (l >> 5);
#pragma unroll
    for (int n = 0; n < NW; ++n) {
      int colg = bcol + (wc * NW + n) * 32 + (l & 31);
      float badd = BIAS ? bias[colg] : 0.f;
#pragma unroll
      for (int r = 0; r < 16; ++r) {
        int rowg = r0 + (r & 3) + 8 * (r >> 2);
        if (rowg < M) C[(size_t)rowg * N + colg] = acc[m][n][r] + badd;
      }
    }
  }
}

// ===========================================================================
// fp32 tiled GEMM (fallback tier)
// ===========================================================================
template <bool ACC>
__global__ __launch_bounds__(256) void gemm_kernel(
    const float* __restrict__ A, const float* __restrict__ W,
    const float* __restrict__ bias, float* __restrict__ C,
    int M, int K, int Nc) {
  __shared__ float As[16][68];
  __shared__ float Bs[16][68];
  int t = threadIdx.x;
  int tx = t & 15, ty = t >> 4;
  int brow = blockIdx.y * 64, bcol = blockIdx.x * 64;
  float acc[4][4] = {};
  int arow = t >> 2;
  int akg  = (t & 3) * 4;
  int bkr  = t >> 4;
  int bcg  = (t & 15) * 4;
  for (int k0 = 0; k0 < K; k0 += 16) {
    float4 a;
    if (brow + arow < M)
      a = *reinterpret_cast<const float4*>(A + (size_t)(brow + arow) * K + k0 + akg);
    else
      a = float4{0.f, 0.f, 0.f, 0.f};
    As[akg + 0][arow] = a.x;
    As[akg + 1][arow] = a.y;
    As[akg + 2][arow] = a.z;
    As[akg + 3][arow] = a.w;
    float4 b = *reinterpret_cast<const float4*>(W + (size_t)(k0 + bkr) * Nc + bcol + bcg);
    *reinterpret_cast<float4*>(&Bs[bkr][bcg]) = b;
    __syncthreads();
#pragma unroll
    for (int k = 0; k < 16; ++k) {
      float4 av = *reinterpret_cast<const float4*>(&As[k][ty * 4]);
      float4 bv = *reinterpret_cast<const float4*>(&Bs[k][tx * 4]);
      float aa[4] = {av.x, av.y, av.z, av.w};
      float bb[4] = {bv.x, bv.y, bv.z, bv.w};
#pragma unroll
      for (int i = 0; i < 4; ++i)
#pragma unroll
        for (int j = 0; j < 4; ++j) acc[i][j] += aa[i] * bb[j];
    }
    __syncthreads();
  }
#pragma unroll
  for (int i = 0; i < 4; ++i) {
    int row = brow + ty * 4 + i;
    if (row >= M) continue;
#pragma unroll
    for (int j = 0; j < 4; ++j) {
      int col = bcol + tx * 4 + j;
      float v = acc[i][j];
      if (bias) v += bias[col];
      if (ACC) v += C[(size_t)row * Nc + col];
      C[(size_t)row * Nc + col] = v;
    }
  }
}

// ===========================================================================
// decode MLP: 8 nodes per block to amortize d1_W traffic (131KB per block)
// ===========================================================================
#define DEC_NODES 8
__global__ __launch_bounds__(128) void decode_kernel(
    const float* __restrict__ outg, const float* __restrict__ d1_W,
    const float* __restrict__ d1_b, const float* __restrict__ d2_W,
    const float* __restrict__ d2_b, float* __restrict__ z1) {
  __shared__ float rows[DEC_NODES][OUT_DIM];
  __shared__ float s0[128], s1[128];
  int t = threadIdx.x;
  int n0 = blockIdx.x * DEC_NODES;
  // load 8 rows (8*256 floats) with 128 threads * 4 float4
#pragma unroll
  for (int j = 0; j < 4; ++j) {
    int idx = j * 512 + t * 4;
    *reinterpret_cast<float4*>(&rows[0][idx]) =
        *reinterpret_cast<const float4*>(outg + (size_t)n0 * OUT_DIM + idx);
  }
  __syncthreads();
  float acc[DEC_NODES];
  float b1 = d1_b[t];
#pragma unroll
  for (int n = 0; n < DEC_NODES; ++n) acc[n] = b1;
#pragma unroll 4
  for (int k = 0; k < OUT_DIM; ++k) {
    float wv = d1_W[k * 128 + t];
#pragma unroll
    for (int n = 0; n < DEC_NODES; ++n) acc[n] += rows[n][k] * wv;
  }
  float w0 = d2_W[t * 2 + 0], w1 = d2_W[t * 2 + 1];
  for (int n = 0; n < DEC_NODES; ++n) {
    float a = fmaxf(acc[n], 0.f);
    s0[t] = a * w0;
    s1[t] = a * w1;
    __syncthreads();
    for (int off = 64; off > 0; off >>= 1) {
      if (t < off) {
        s0[t] += s0[t + off];
        s1[t] += s1[t + off];
      }
      __syncthreads();
    }
    if (t == 0) {
      z1[(size_t)(n0 + n) * 2 + 0] = s0[0] + d2_b[0];
      z1[(size_t)(n0 + n) * 2 + 1] = s1[0] + d2_b[1];
    }
    __syncthreads();
  }
}

// ===========================================================================
// Atomic-path fallback kernels (lowest tier)
// ===========================================================================
__global__ __launch_bounds__(128) void scatter_x_kernel(
    const float* __restrict__ x, const int* __restrict__ src,
    const int* __restrict__ dst, float* __restrict__ agg,
    float* __restrict__ deg) {
  int e = blockIdx.x;
  int t = threadIdx.x;
  int s = src[e], d = dst[e];
  const float4 v = *reinterpret_cast<const float4*>(x + (size_t)s * IN_DIM + t * 4);
  float* ap = agg + (size_t)d * IN_DIM + t * 4;
  atomicAdd(ap + 0, v.x);
  atomicAdd(ap + 1, v.y);
  atomicAdd(ap + 2, v.z);
  atomicAdd(ap + 3, v.w);
  if (t == 0) atomicAdd(deg + d, 1.0f);
}

__global__ void dis_kernel(float* __restrict__ deg) {
  int i = blockIdx.x * 256 + threadIdx.x;
  if (i < N_NODES) deg[i] = rsqrtf(deg[i] + 1.0f);
}

__global__ __launch_bounds__(64) void out_init_kernel(
    const float* __restrict__ h, const float* __restrict__ dis,
    const float* __restrict__ gcn_b, float* __restrict__ out) {
  int i = blockIdx.x;
  int t = threadIdx.x;
  float di = dis[i];
  float nrm = di * di;
  float4 hv = *reinterpret_cast<const float4*>(h + (size_t)i * OUT_DIM + t * 4);
  float4 bv = *reinterpret_cast<const float4*>(gcn_b + t * 4);
  float4 o{hv.x * nrm + bv.x, hv.y * nrm + bv.y, hv.z * nrm + bv.z, hv.w * nrm + bv.w};
  *reinterpret_cast<float4*>(out + (size_t)i * OUT_DIM + t * 4) = o;
}

__global__ __launch_bounds__(64) void scatter_h_kernel(
    const float* __restrict__ h, const int* __restrict__ src,
    const int* __restrict__ dst, const float* __restrict__ dis,
    float* __restrict__ out) {
  int e = blockIdx.x;
  int t = threadIdx.x;
  int s = src[e], d = dst[e];
  float nrm = dis[s] * dis[d];
  float4 v = *reinterpret_cast<const float4*>(h + (size_t)s * OUT_DIM + t * 4);
  float* op = out + (size_t)d * OUT_DIM + t * 4;
  atomicAdd(op + 0, v.x * nrm);
  atomicAdd(op + 1, v.y * nrm);
  atomicAdd(op + 2, v.z * nrm);
  atomicAdd(op + 3, v.w * nrm);
}

// ===========================================================================
extern "C" void kernel_launch(void* const* d_in, const int* in_sizes, int n_in,
                              void* d_out, int out_size, void* d_ws, size_t ws_size,
                              hipStream_t stream) {
  const float* x     = (const float*)d_in[0];
  const int*   edge  = (const int*)d_in[1];
  const float* f_W   = (const float*)d_in[2];
  const float* f_b   = (const float*)d_in[3];
  const float* gcn_W = (const float*)d_in[4];
  const float* gcn_b = (const float*)d_in[5];
  const float* d1_W  = (const float*)d_in[6];
  const float* d1_b  = (const float*)d_in[7];
  const float* d2_W  = (const float*)d_in[8];
  const float* d2_b  = (const float*)d_in[9];
  float* out = (float*)d_out;
  float* ws  = (float*)d_ws;

  const int* src = edge;
  const int* dst = edge + E_EDGES;

  // float ws layout: agg [0,512N) -> reused as h [0,256N) + outg [256N,512N)
  //                  h1 [512N,1024N);  dis [1024N,1025N)
  float* agg  = ws;
  float* h1   = ws + (size_t)512 * N_NODES;
  float* dis  = ws + (size_t)1024 * N_NODES;
  float* h    = ws;
  float* outg = ws + (size_t)256 * N_NODES;

  // int CSR region
  int* icount = (int*)(ws + (size_t)1025 * N_NODES);  // N ints
  int* irow   = icount + N_NODES;                     // N+1 ints
  int* icol   = irow + N_NODES + 1;                   // E ints
  size_t csr_needed = (size_t)1025 * N_NODES * sizeof(float) +
                      (size_t)(2 * N_NODES + 1 + E_EDGES) * sizeof(int);

  // bf16 weight region (16B aligned)
  const size_t WELEMS = 512 * 512;  // == 1024*256
  size_t usOff = (csr_needed + 15) & ~(size_t)15;
  unsigned short* fWt_hi = (unsigned short*)((char*)d_ws + usOff);
  unsigned short* fWt_lo = fWt_hi + WELEMS;
  unsigned short* gWt_hi = fWt_lo + WELEMS;
  unsigned short* gWt_lo = gWt_hi + WELEMS;
  size_t mfma_needed = usOff + 4 * WELEMS * sizeof(unsigned short);

  if (ws_size >= csr_needed) {
    // ---- CSR build
    hipMemsetAsync(icount, 0, (size_t)N_NODES * sizeof(int), stream);
    count_kernel<<<(E_EDGES + 255) / 256, 256, 0, stream>>>(dst, icount);
    scan_kernel<<<1, 1024, 0, stream>>>(icount, irow, dis);
    place_kernel<<<(E_EDGES + 255) / 256, 256, 0, stream>>>(src, dst, icount, icol);

    // ---- GIN aggregation (gather, no atomics)
    gin_gather_kernel<<<N_NODES, 128, 0, stream>>>(x, irow, icol, agg);

    if (ws_size >= mfma_needed) {
      // ---- weight transpose + bf16 split
      convT_kernel<<<dim3(IN_DIM / 256, HID_DIM), 256, 0, stream>>>(
          f_W, fWt_hi, fWt_lo, IN_DIM, HID_DIM);
      convT_kernel<<<dim3((IN_DIM + HID_DIM) / 256, OUT_DIM), 256, 0, stream>>>(
          gcn_W, gWt_hi, gWt_lo, IN_DIM + HID_DIM, OUT_DIM);

      // ---- h1 = agg @ f_W + f_b      (BN=128, grid 4 x 79)
      mfma_gemm_kernel<true, 2><<<dim3(HID_DIM / 128, (N_NODES + 127) / 128), 256, 0, stream>>>(
          agg, agg, IN_DIM, fWt_hi, fWt_lo, f_b, h1, N_NODES, IN_DIM, HID_DIM);

      // ---- h = [x | h1] @ gcn_W      (BN=64, grid 4 x 79)
      mfma_gemm_kernel<false, 1><<<dim3(OUT_DIM / 64, (N_NODES + 127) / 128), 256, 0, stream>>>(
          x, h1, IN_DIM, gWt_hi, gWt_lo, nullptr, h, N_NODES, IN_DIM + HID_DIM, OUT_DIM);
    } else {
      gemm_kernel<false><<<dim3(HID_DIM / 64, (N_NODES + 63) / 64), 256, 0, stream>>>(
          agg, f_W, f_b, h1, N_NODES, IN_DIM, HID_DIM);
      gemm_kernel<false><<<dim3(OUT_DIM / 64, (N_NODES + 63) / 64), 256, 0, stream>>>(
          x, gcn_W, nullptr, h, N_NODES, IN_DIM, OUT_DIM);
      gemm_kernel<true><<<dim3(OUT_DIM / 64, (N_NODES + 63) / 64), 256, 0, stream>>>(
          h1, gcn_W + (size_t)IN_DIM * OUT_DIM, nullptr, h, N_NODES, HID_DIM, OUT_DIM);
    }

    // ---- GCN aggregation (gather, fused self-loop + bias)
    gcn_gather_kernel<<<N_NODES, 64, 0, stream>>>(h, irow, icol, dis, gcn_b, outg);

    // ---- decode (8 nodes/block)
    decode_kernel<<<N_NODES / DEC_NODES, 128, 0, stream>>>(outg, d1_W, d1_b, d2_W, d2_b, out);
  } else {
    // ---- lowest tier: atomic path
    float* deg = dis;
    hipMemsetAsync(agg, 0, (size_t)512 * N_NODES * sizeof(float), stream);
    hipMemsetAsync(deg, 0, (size_t)N_NODES * sizeof(float), stream);
    scatter_x_kernel<<<E_EDGES, 128, 0, stream>>>(x, src, dst, agg, deg);
    dis_kernel<<<(N_NODES + 255) / 256, 256, 0, stream>>>(deg);
    gemm_kernel<false><<<dim3(HID_DIM / 64, (N_NODES + 63) / 64), 256, 0, stream>>>(
        agg, f_W, f_b, h1, N_NODES, IN_DIM, HID_DIM);
    gemm_kernel<false><<<dim3(OUT_DIM / 64, (N_NODES + 63) / 64), 256, 0, stream>>>(
        x, gcn_W, nullptr, h, N_NODES, IN_DIM, OUT_DIM);
    gemm_kernel<true><<<dim3(OUT_DIM / 64, (N_NODES + 63) / 64), 256, 0, stream>>>(
        h1, gcn_W + (size_t)IN_DIM * OUT_DIM, nullptr, h, N_NODES, HID_DIM, OUT_DIM);
    out_init_kernel<<<N_NODES, 64, 0, stream>>>(h, dis, gcn_b, outg);
    scatter_h_kernel<<<E_EDGES, 64, 0, stream>>>(h, src, dst, dis, outg);
    decode_kernel<<<N_NODES / DEC_NODES, 128, 0, stream>>>(outg, d1_W, d1_b, d2_W, d2_b, out);
  }
}